// Round 5
// baseline (686.855 us; speedup 1.0000x reference)
//
#include <hip/hip_runtime.h>

#define NN 100000   // nodes
#define NE 200000   // edges per etype
#define NT 3        // etypes
#define DD 128      // feature dim
#define NL 3        // layers
#define EPSV 1e-5f
#define SCB 98      // ceil(NN / 1024) scan chunks per etype

typedef __attribute__((ext_vector_type(8))) short short8;
typedef __attribute__((ext_vector_type(4))) float f32x4;

__device__ __forceinline__ float bf2f(unsigned short u) {
  unsigned v = ((unsigned)u) << 16;
  return __builtin_bit_cast(float, v);
}
__device__ __forceinline__ unsigned short f2bf(float f) {
  unsigned u = __builtin_bit_cast(unsigned, f);
  u += 0x7FFF + ((u >> 16) & 1);  // round-to-nearest-even
  return (unsigned short)(u >> 16);
}

// ---------------- CSR build ----------------

__global__ __launch_bounds__(256) void count_kernel(const int* __restrict__ dst,
                                                    int* __restrict__ cnt) {
  int gid = blockIdx.x * 256 + threadIdx.x;
  if (gid >= NT * NE) return;
  int et = gid / NE;
  atomicAdd(&cnt[et * NN + dst[gid]], 1);
}

__global__ __launch_bounds__(256) void scanA(const int* __restrict__ cnt,
                                             int* __restrict__ rp,
                                             int* __restrict__ aux) {
  __shared__ int sm[256];
  int et = blockIdx.x / SCB, ch = blockIdx.x % SCB;
  const int* c = cnt + et * NN;
  int* r = rp + et * (NN + 1);
  int t = threadIdx.x;
  int base = ch * 1024;
  int v[4];
  int s = 0;
  #pragma unroll
  for (int j = 0; j < 4; ++j) {
    int i = base + t * 4 + j;
    v[j] = (i < NN) ? c[i] : 0;
    s += v[j];
  }
  sm[t] = s;
  __syncthreads();
  #pragma unroll
  for (int off = 1; off < 256; off <<= 1) {
    int x = 0;
    if (t >= off) x = sm[t - off];
    __syncthreads();
    if (t >= off) sm[t] += x;
    __syncthreads();
  }
  int run = sm[t] - s;
  if (t == 255) aux[et * SCB + ch] = sm[255];
  #pragma unroll
  for (int j = 0; j < 4; ++j) {
    int i = base + t * 4 + j;
    if (i < NN) r[i] = run;
    run += v[j];
  }
}

__global__ __launch_bounds__(64) void scanB(int* __restrict__ aux, int* __restrict__ rp) {
  int et = threadIdx.x;
  if (et >= NT) return;
  int run = 0;
  for (int ch = 0; ch < SCB; ++ch) {
    int x = aux[et * SCB + ch];
    aux[et * SCB + ch] = run;
    run += x;
  }
  rp[et * (NN + 1) + NN] = run;
}

__global__ __launch_bounds__(256) void scanC(int* __restrict__ rp, const int* __restrict__ aux) {
  int et = blockIdx.x / SCB, ch = blockIdx.x % SCB;
  int off = aux[et * SCB + ch];
  int* r = rp + et * (NN + 1);
  int base = ch * 1024 + threadIdx.x * 4;
  #pragma unroll
  for (int j = 0; j < 4; ++j) {
    int i = base + j;
    if (i < NN) r[i] += off;
  }
}

__global__ __launch_bounds__(256) void fill_kernel(const int* __restrict__ src,
                                                   const int* __restrict__ dst,
                                                   const int* __restrict__ rp,
                                                   int* __restrict__ cursor,
                                                   int* __restrict__ col) {
  int gid = blockIdx.x * 256 + threadIdx.x;
  if (gid >= NT * NE) return;
  int et = gid / NE;
  int d = dst[gid];
  int pos = rp[et * (NN + 1) + d] + atomicAdd(&cursor[et * NN + d], 1);
  col[et * NE + pos] = src[gid];
}

// ---------------- conversions ----------------

__global__ __launch_bounds__(256) void convert_f2b(const float* __restrict__ x,
                                                   unsigned short* __restrict__ y) {
  const int n4 = NN * DD / 4;
  for (int i = blockIdx.x * 256 + threadIdx.x; i < n4; i += gridDim.x * 256) {
    float4 v = ((const float4*)x)[i];
    ushort4 o = make_ushort4(f2bf(v.x), f2bf(v.y), f2bf(v.z), f2bf(v.w));
    ((ushort4*)y)[i] = o;
  }
}

// fp32 [K][N] -> bf16 transposed [N][K], PRE-SWIZZLED: within row n, the 16B
// k-slot s lands at position s^(n&7). Staging into LDS is then a linear copy
// and the gemm's ds_read applies the same XOR. m = (l*NT+e)*2 + which.
__global__ __launch_bounds__(256) void convert_wt(const float* __restrict__ Ws,
                                                  const float* __restrict__ Wn,
                                                  unsigned short* __restrict__ wt) {
  int gid = blockIdx.x * 256 + threadIdx.x;
  if (gid >= 2 * NL * NT * DD * DD) return;
  int k0 = gid & 7;
  int sd = (gid >> 3) & 15;
  int n  = (gid >> 7) & 127;
  int m  = gid >> 14;
  int k  = ((sd ^ (n & 7)) << 3) | k0;
  const float* W = (m & 1) ? Wn : Ws;
  int le = m >> 1;
  wt[gid] = f2bf(W[((size_t)le << 14) + (k << 7) + n]);
}

// ---------------- fused gather + MFMA SAGE layer ----------------
// Per block (128-row tile, 512 thr, 8 waves), per etype e:
//   1. stage pre-swizzled Ws^T|Wn^T (64 KB) into wbuf (linear copy)
//   2. gather-aggregate ng tile for this block's 128 nodes into sN (bf16, swz)
//   3. barrier; self-half (h regs x Ws) + neigh-half (nf from sN x Wn) MFMAs
// P = sum_e act(...); BN column stats fused into the epilogue.

template <bool ACT>
__global__ __launch_bounds__(512, 2) void gemm_fused(const unsigned short* __restrict__ hbf,
                                                     const int* __restrict__ rp,
                                                     const int* __restrict__ col,
                                                     const unsigned short* __restrict__ wtl,
                                                     const float* __restrict__ bl,
                                                     float* __restrict__ P,
                                                     float* __restrict__ gsums) {
  __shared__ unsigned short wbuf[256 * DD];   // 64 KB weights (pre-swizzled)
  __shared__ unsigned short sN[128 * DD];     // 32 KB aggregated-neighbor tile
  int tid = threadIdx.x;
  int lane = tid & 63, wv = tid >> 6;
  int ln15 = lane & 15, kg = lane >> 4;  // kg 0..3
  int rx = ln15 & 7;
  int row0 = blockIdx.x * 128;
  int arow = row0 + wv * 16 + ln15;      // output row this lane serves
  int crow = (arow < NN) ? arow : 0;     // clamped for safe loads
  int arowL = wv * 16 + ln15;            // row within tile

  // h fragments: 16 VGPR, loaded once
  const unsigned short* hrow = hbf + (size_t)crow * DD;
  short8 hf[4];
  #pragma unroll
  for (int ks = 0; ks < 4; ++ks)
    hf[ks] = *(const short8*)(hrow + ks * 32 + kg * 8);

  f32x4 out[8];

  #pragma unroll 1
  for (int e = 0; e < NT; ++e) {
    if (e > 0) __syncthreads();  // prior reads of wbuf/sN complete

    // ---- gather-aggregate ng tile for this etype ----
    {
      int grp = tid >> 4, gl = tid & 15;  // 32 groups x 16 lanes; 4 nodes/group
      const int* rpe = rp + e * (NN + 1);
      const int* ce = col + e * NE;
      #pragma unroll 1
      for (int i = 0; i < 4; ++i) {
        int n = grp * 4 + i;
        int grow = row0 + n;
        float a0 = 0.f, a1 = 0.f, a2 = 0.f, a3 = 0.f;
        float a4 = 0.f, a5 = 0.f, a6 = 0.f, a7 = 0.f;
        int deg = 0;
        if (grow < NN) {
          int bg = rpe[grow], en = rpe[grow + 1];
          deg = en - bg;
          int e2 = bg;
          for (; e2 + 1 < en; e2 += 2) {
            int c0 = ce[e2], c1 = ce[e2 + 1];
            short8 v0 = *(const short8*)(hbf + (size_t)c0 * DD + gl * 8);
            short8 v1 = *(const short8*)(hbf + (size_t)c1 * DD + gl * 8);
            a0 += bf2f((unsigned short)v0[0]) + bf2f((unsigned short)v1[0]);
            a1 += bf2f((unsigned short)v0[1]) + bf2f((unsigned short)v1[1]);
            a2 += bf2f((unsigned short)v0[2]) + bf2f((unsigned short)v1[2]);
            a3 += bf2f((unsigned short)v0[3]) + bf2f((unsigned short)v1[3]);
            a4 += bf2f((unsigned short)v0[4]) + bf2f((unsigned short)v1[4]);
            a5 += bf2f((unsigned short)v0[5]) + bf2f((unsigned short)v1[5]);
            a6 += bf2f((unsigned short)v0[6]) + bf2f((unsigned short)v1[6]);
            a7 += bf2f((unsigned short)v0[7]) + bf2f((unsigned short)v1[7]);
          }
          if (e2 < en) {
            short8 v0 = *(const short8*)(hbf + (size_t)ce[e2] * DD + gl * 8);
            a0 += bf2f((unsigned short)v0[0]);
            a1 += bf2f((unsigned short)v0[1]);
            a2 += bf2f((unsigned short)v0[2]);
            a3 += bf2f((unsigned short)v0[3]);
            a4 += bf2f((unsigned short)v0[4]);
            a5 += bf2f((unsigned short)v0[5]);
            a6 += bf2f((unsigned short)v0[6]);
            a7 += bf2f((unsigned short)v0[7]);
          }
        }
        float inv = 1.0f / (float)(deg > 1 ? deg : 1);
        uint4 pk;
        pk.x = (unsigned)f2bf(a0 * inv) | ((unsigned)f2bf(a1 * inv) << 16);
        pk.y = (unsigned)f2bf(a2 * inv) | ((unsigned)f2bf(a3 * inv) << 16);
        pk.z = (unsigned)f2bf(a4 * inv) | ((unsigned)f2bf(a5 * inv) << 16);
        pk.w = (unsigned)f2bf(a6 * inv) | ((unsigned)f2bf(a7 * inv) << 16);
        *(uint4*)(sN + n * DD + ((gl ^ (n & 7)) << 3)) = pk;
      }
    }

    // ---- stage weights (pre-swizzled -> linear copy) ----
    {
      const uint4* wsrc = (const uint4*)(wtl + (size_t)e * 2 * DD * DD);
      uint4* wdst = (uint4*)wbuf;
      #pragma unroll
      for (int it = 0; it < 8; ++it)
        wdst[it * 512 + tid] = wsrc[it * 512 + tid];
    }
    __syncthreads();  // weights + sN visible

    // bias -> accumulator init
    const float* be = bl + e * DD;
    f32x4 acc[8];
    #pragma unroll
    for (int c = 0; c < 8; ++c) {
      float bv = be[c * 16 + ln15];
      acc[c] = (f32x4){bv, bv, bv, bv};
    }

    // nf fragments from sN (swizzled ds_read)
    short8 nf[4];
    #pragma unroll
    for (int ks = 0; ks < 4; ++ks)
      nf[ks] = *(const short8*)(sN + arowL * DD + (((ks * 4 + kg) ^ rx) << 3));

    // self half: h @ Ws_e
    #pragma unroll
    for (int ks = 0; ks < 4; ++ks) {
      int so = ((ks * 4 + kg) ^ rx) << 3;
      #pragma unroll
      for (int c = 0; c < 8; ++c) {
        short8 bfr = *(const short8*)(&wbuf[(c * 16 + ln15) * DD + so]);
        acc[c] = __builtin_amdgcn_mfma_f32_16x16x32_bf16(hf[ks], bfr, acc[c], 0, 0, 0);
      }
    }
    // neigh half: ng_e @ Wn_e
    #pragma unroll
    for (int ks = 0; ks < 4; ++ks) {
      int so = ((ks * 4 + kg) ^ rx) << 3;
      #pragma unroll
      for (int c = 0; c < 8; ++c) {
        short8 bfr = *(const short8*)(&wbuf[(128 + c * 16 + ln15) * DD + so]);
        acc[c] = __builtin_amdgcn_mfma_f32_16x16x32_bf16(nf[ks], bfr, acc[c], 0, 0, 0);
      }
    }

    // per-etype activation, merge into out
    #pragma unroll
    for (int c = 0; c < 8; ++c) {
      #pragma unroll
      for (int r = 0; r < 4; ++r) {
        float v = acc[c][r];
        if (ACT) v = fmaxf(v, 0.f);
        out[c][r] = (e == 0) ? v : (out[c][r] + v);
      }
    }
  }

  __syncthreads();  // done with wbuf/sN; reuse wbuf as fp32 [128][128] scratch
  float* scr = (float*)wbuf;

  // scatter fragments (C/D layout: col=lane&15, row=(lane>>4)*4+reg)
  int drow = wv * 16 + kg * 4;
  #pragma unroll
  for (int c = 0; c < 8; ++c) {
    int colx = c * 16 + ln15;
    #pragma unroll
    for (int r = 0; r < 4; ++r) scr[(drow + r) * DD + colx] = out[c][r];
  }
  __syncthreads();

  // coalesced write-out + per-thread column partial sums for BN
  int ty = tid >> 5;
  int c4 = (tid & 31) * 4;
  f32x4 s = (f32x4){0.f, 0.f, 0.f, 0.f};
  f32x4 s2 = (f32x4){0.f, 0.f, 0.f, 0.f};
  #pragma unroll
  for (int it = 0; it < 8; ++it) {
    int row = it * 16 + ty;
    int grow = row0 + row;
    if (grow < NN) {
      f32x4 v = *(const f32x4*)(scr + row * DD + c4);
      *(f32x4*)(P + (size_t)grow * DD + c4) = v;
      s += v;
      s2 += v * v;
    }
  }
  __syncthreads();
  *(f32x4*)(scr + ty * DD + c4) = s;
  *(f32x4*)(scr + 16 * DD + ty * DD + c4) = s2;
  __syncthreads();
  if (tid < DD) {
    float ts = 0.f, ts2 = 0.f;
    #pragma unroll
    for (int g = 0; g < 16; ++g) {
      ts += scr[g * DD + tid];
      ts2 += scr[16 * DD + g * DD + tid];
    }
    atomicAdd(gsums + tid, ts);
    atomicAdd(gsums + DD + tid, ts2);
  }
}

// ---------------- batchnorm finalize / apply ----------------

__global__ __launch_bounds__(128) void bn_finalize_kernel(const float* __restrict__ sums,
                                                          const float* __restrict__ gamma,
                                                          const float* __restrict__ beta,
                                                          float* __restrict__ ss) {
  int c = threadIdx.x;
  float mean = sums[c] * (1.0f / NN);
  float var = sums[DD + c] * (1.0f / NN) - mean * mean;
  float sc = gamma[c] * rsqrtf(var + EPSV);
  ss[c] = sc;
  ss[DD + c] = beta[c] - mean * sc;
}

template <bool LASTL>
__global__ __launch_bounds__(256) void bn_apply(const float* __restrict__ P,
                                                const float* __restrict__ ss,
                                                unsigned short* __restrict__ hb,
                                                float* __restrict__ outp) {
  const int n4 = NN * DD / 4;
  for (int i = blockIdx.x * 256 + threadIdx.x; i < n4; i += gridDim.x * 256) {
    int c4 = (i & 31) << 2;
    float4 v = ((const float4*)P)[i];
    float4 sc = *(const float4*)(ss + c4);
    float4 sh = *(const float4*)(ss + DD + c4);
    v.x = v.x * sc.x + sh.x;
    v.y = v.y * sc.y + sh.y;
    v.z = v.z * sc.z + sh.z;
    v.w = v.w * sc.w + sh.w;
    if (LASTL) {
      ((float4*)outp)[i] = v;
    } else {
      ushort4 o = make_ushort4(f2bf(v.x), f2bf(v.y), f2bf(v.z), f2bf(v.w));
      ((ushort4*)hb)[i] = o;
    }
  }
}

// ---------------- launch ----------------

static inline size_t align_up(size_t x, size_t a) { return (x + a - 1) & ~(a - 1); }

extern "C" void kernel_launch(void* const* d_in, const int* in_sizes, int n_in,
                              void* d_out, int out_size, void* d_ws, size_t ws_size,
                              hipStream_t stream) {
  const float* feat    = (const float*)d_in[0];
  const int*   src     = (const int*)d_in[1];
  const int*   dst     = (const int*)d_in[2];
  const float* W_self  = (const float*)d_in[3];
  const float* W_neigh = (const float*)d_in[4];
  const float* b       = (const float*)d_in[5];
  const float* gamma   = (const float*)d_in[6];
  const float* beta    = (const float*)d_in[7];

  float* P = (float*)d_out;  // fp32 pre-BN accumulator in d_out

  char* w = (char*)d_ws;
  size_t off = 0;
  unsigned short* hbf = (unsigned short*)(w + off); off = align_up(off + (size_t)NN * DD * 2, 256);
  unsigned short* wt  = (unsigned short*)(w + off); off = align_up(off + (size_t)2 * NL * NT * DD * DD * 2, 256);
  int* rp  = (int*)(w + off); off = align_up(off + (size_t)NT * (NN + 1) * 4, 256);
  int* col = (int*)(w + off); off = align_up(off + (size_t)NT * NE * 4, 256);
  float* gsums = (float*)(w + off); off = align_up(off + 256 * 4, 256);
  float* ss    = (float*)(w + off); off = align_up(off + 256 * 4, 256);
  int* cnt = (int*)(w + off); off = align_up(off + (size_t)NT * NN * 4, 256);
  int* aux = (int*)(w + off); off = align_up(off + (size_t)NT * SCB * 4, 256);

  // ---- CSR build ----
  hipMemsetAsync(cnt, 0, (size_t)NT * NN * 4, stream);
  count_kernel<<<(NT * NE + 255) / 256, 256, 0, stream>>>(dst, cnt);
  scanA<<<NT * SCB, 256, 0, stream>>>(cnt, rp, aux);
  scanB<<<1, 64, 0, stream>>>(aux, rp);
  scanC<<<NT * SCB, 256, 0, stream>>>(rp, aux);
  hipMemsetAsync(cnt, 0, (size_t)NT * NN * 4, stream);
  fill_kernel<<<(NT * NE + 255) / 256, 256, 0, stream>>>(src, dst, rp, cnt, col);

  // ---- conversions ----
  convert_wt<<<(2 * NL * NT * DD * DD + 255) / 256, 256, 0, stream>>>(W_self, W_neigh, wt);
  convert_f2b<<<1024, 256, 0, stream>>>(feat, hbf);

  const int gemm_grid = (NN + 127) / 128;
  for (int l = 0; l < NL; ++l) {
    bool act = (l < NL - 1);
    hipMemsetAsync(gsums, 0, 256 * 4, stream);
    const unsigned short* wtl = wt + (size_t)l * NT * 2 * DD * DD;
    const float* bl = b + (size_t)l * NT * DD;
    if (act) gemm_fused<true><<<gemm_grid, 512, 0, stream>>>(hbf, rp, col, wtl, bl, P, gsums);
    else     gemm_fused<false><<<gemm_grid, 512, 0, stream>>>(hbf, rp, col, wtl, bl, P, gsums);
    bn_finalize_kernel<<<1, 128, 0, stream>>>(gsums, gamma + l * DD, beta + l * DD, ss);
    if (l == NL - 1) bn_apply<true><<<1024, 256, 0, stream>>>(P, ss, hbf, P);
    else             bn_apply<false><<<1024, 256, 0, stream>>>(P, ss, hbf, P);
  }
}

// Round 6
// 550.269 us; speedup vs baseline: 1.2482x; 1.2482x over previous
//
#include <hip/hip_runtime.h>

#define NN 100000   // nodes
#define NE 200000   // edges per etype
#define NT 3        // etypes
#define DD 128      // feature dim
#define NL 3        // layers
#define EPSV 1e-5f
#define SCB 98      // ceil(NN / 1024) scan chunks per etype

typedef __attribute__((ext_vector_type(8))) short short8;
typedef __attribute__((ext_vector_type(4))) float f32x4;

__device__ __forceinline__ float bf2f(unsigned short u) {
  unsigned v = ((unsigned)u) << 16;
  return __builtin_bit_cast(float, v);
}
__device__ __forceinline__ unsigned short f2bf(float f) {
  unsigned u = __builtin_bit_cast(unsigned, f);
  u += 0x7FFF + ((u >> 16) & 1);  // round-to-nearest-even
  return (unsigned short)(u >> 16);
}
__device__ __forceinline__ unsigned pkbf(float a, float b) {
  return (unsigned)f2bf(a) | ((unsigned)f2bf(b) << 16);
}

// ---------------- CSR build ----------------

__global__ __launch_bounds__(256) void count_kernel(const int* __restrict__ dst,
                                                    int* __restrict__ cnt) {
  int gid = blockIdx.x * 256 + threadIdx.x;
  if (gid >= NT * NE) return;
  int et = gid / NE;
  atomicAdd(&cnt[et * NN + dst[gid]], 1);
}

__global__ __launch_bounds__(256) void scanA(const int* __restrict__ cnt,
                                             int* __restrict__ rp,
                                             int* __restrict__ aux) {
  __shared__ int sm[256];
  int et = blockIdx.x / SCB, ch = blockIdx.x % SCB;
  const int* c = cnt + et * NN;
  int* r = rp + et * (NN + 1);
  int t = threadIdx.x;
  int base = ch * 1024;
  int v[4];
  int s = 0;
  #pragma unroll
  for (int j = 0; j < 4; ++j) {
    int i = base + t * 4 + j;
    v[j] = (i < NN) ? c[i] : 0;
    s += v[j];
  }
  sm[t] = s;
  __syncthreads();
  #pragma unroll
  for (int off = 1; off < 256; off <<= 1) {
    int x = 0;
    if (t >= off) x = sm[t - off];
    __syncthreads();
    if (t >= off) sm[t] += x;
    __syncthreads();
  }
  int run = sm[t] - s;
  if (t == 255) aux[et * SCB + ch] = sm[255];
  #pragma unroll
  for (int j = 0; j < 4; ++j) {
    int i = base + t * 4 + j;
    if (i < NN) r[i] = run;
    run += v[j];
  }
}

__global__ __launch_bounds__(64) void scanB(int* __restrict__ aux, int* __restrict__ rp) {
  int et = threadIdx.x;
  if (et >= NT) return;
  int run = 0;
  for (int ch = 0; ch < SCB; ++ch) {
    int x = aux[et * SCB + ch];
    aux[et * SCB + ch] = run;
    run += x;
  }
  rp[et * (NN + 1) + NN] = run;
}

__global__ __launch_bounds__(256) void scanC(int* __restrict__ rp, const int* __restrict__ aux) {
  int et = blockIdx.x / SCB, ch = blockIdx.x % SCB;
  int off = aux[et * SCB + ch];
  int* r = rp + et * (NN + 1);
  int base = ch * 1024 + threadIdx.x * 4;
  #pragma unroll
  for (int j = 0; j < 4; ++j) {
    int i = base + j;
    if (i < NN) r[i] += off;
  }
}

__global__ __launch_bounds__(256) void fill_kernel(const int* __restrict__ src,
                                                   const int* __restrict__ dst,
                                                   const int* __restrict__ rp,
                                                   int* __restrict__ cursor,
                                                   int* __restrict__ col) {
  int gid = blockIdx.x * 256 + threadIdx.x;
  if (gid >= NT * NE) return;
  int et = gid / NE;
  int d = dst[gid];
  int pos = rp[et * (NN + 1) + d] + atomicAdd(&cursor[et * NN + d], 1);
  col[et * NE + pos] = src[gid];
}

// ---------------- conversions ----------------

__global__ __launch_bounds__(256) void convert_f2b(const float* __restrict__ x,
                                                   unsigned short* __restrict__ y) {
  const int n4 = NN * DD / 4;
  for (int i = blockIdx.x * 256 + threadIdx.x; i < n4; i += gridDim.x * 256) {
    float4 v = ((const float4*)x)[i];
    ushort4 o = make_ushort4(f2bf(v.x), f2bf(v.y), f2bf(v.z), f2bf(v.w));
    ((ushort4*)y)[i] = o;
  }
}

// fp32 [K][N] -> bf16 transposed [N][K], PRE-SWIZZLED: within row n, the 16B
// k-slot s lands at position s^(n&7). Staging into LDS is a linear copy and
// the gemm's ds_read applies the same XOR. m = (l*NT+e)*2 + which.
__global__ __launch_bounds__(256) void convert_wt(const float* __restrict__ Ws,
                                                  const float* __restrict__ Wn,
                                                  unsigned short* __restrict__ wt) {
  int gid = blockIdx.x * 256 + threadIdx.x;
  if (gid >= 2 * NL * NT * DD * DD) return;
  int k0 = gid & 7;
  int sd = (gid >> 3) & 15;
  int n  = (gid >> 7) & 127;
  int m  = gid >> 14;
  int k  = ((sd ^ (n & 7)) << 3) | k0;
  const float* W = (m & 1) ? Wn : Ws;
  int le = m >> 1;
  wt[gid] = f2bf(W[((size_t)le << 14) + (k << 7) + n]);
}

// ---------------- fused gather + MFMA SAGE layer ----------------
// Per block (128-row tile, 512 thr, 8 waves), per etype e:
//   1. stage pre-swizzled Ws^T|Wn^T (64 KB) into wbuf (linear copy)
//   2. each lane gathers its OWN neigh A-fragment slices (mean over edges)
//      directly into registers (fp32 accum, two-walk to cap VGPR) -> nf[4]
//   3. barrier; self-half (hf x Ws) + neigh-half (nf x Wn) MFMAs
// P = sum_e act(...); BN column stats fused into the epilogue.

template <bool ACT>
__global__ __launch_bounds__(512, 4) void gemm_fused(const unsigned short* __restrict__ hbf,
                                                     const int* __restrict__ rp,
                                                     const int* __restrict__ col,
                                                     const unsigned short* __restrict__ wtl,
                                                     const float* __restrict__ bl,
                                                     float* __restrict__ P,
                                                     float* __restrict__ gsums) {
  __shared__ unsigned short wbuf[256 * DD];  // 64 KB weights (pre-swizzled)
  int tid = threadIdx.x;
  int lane = tid & 63, wv = tid >> 6;
  int ln15 = lane & 15, kg = lane >> 4;  // kg 0..3
  int rx = ln15 & 7;
  int row0 = blockIdx.x * 128;
  int arow = row0 + wv * 16 + ln15;      // output row this lane serves
  int crow = (arow < NN) ? arow : 0;     // clamped for safe loads

  // h fragments: 16 VGPR, loaded once
  const unsigned short* hrow = hbf + (size_t)crow * DD;
  short8 hf[4];
  #pragma unroll
  for (int ks = 0; ks < 4; ++ks)
    hf[ks] = *(const short8*)(hrow + ks * 32 + kg * 8);

  f32x4 out[8];

  #pragma unroll 1
  for (int e = 0; e < NT; ++e) {
    if (e > 0) __syncthreads();  // prior reads of wbuf complete

    // ---- stage weights (pre-swizzled -> linear copy) ----
    {
      const uint4* wsrc = (const uint4*)(wtl + (size_t)e * 2 * DD * DD);
      uint4* wdst = (uint4*)wbuf;
      #pragma unroll
      for (int it = 0; it < 8; ++it)
        wdst[it * 512 + tid] = wsrc[it * 512 + tid];
    }

    // ---- per-lane gather of neigh fragments into registers ----
    short8 nf[4];
    {
      const int* rpe = rp + e * (NN + 1);
      const int* ce = col + e * NE;
      int bg = rpe[crow], en = rpe[crow + 1];
      int deg = en - bg;
      float inv = 1.0f / (float)(deg > 1 ? deg : 1);
      #pragma unroll
      for (int hw = 0; hw < 2; ++hw) {  // walk edges twice: slices (0,1),(2,3)
        float ga[16];
        #pragma unroll
        for (int i = 0; i < 16; ++i) ga[i] = 0.f;
        const int b0 = (2 * hw) * 32 + kg * 8;
        const int b1 = (2 * hw + 1) * 32 + kg * 8;
        for (int e2 = bg; e2 < en; ++e2) {
          const unsigned short* hr = hbf + (size_t)ce[e2] * DD;
          short8 v0 = *(const short8*)(hr + b0);
          short8 v1 = *(const short8*)(hr + b1);
          #pragma unroll
          for (int j = 0; j < 8; ++j) {
            ga[j]     += bf2f((unsigned short)v0[j]);
            ga[8 + j] += bf2f((unsigned short)v1[j]);
          }
        }
        uint4 q0, q1;
        q0.x = pkbf(ga[0] * inv, ga[1] * inv);
        q0.y = pkbf(ga[2] * inv, ga[3] * inv);
        q0.z = pkbf(ga[4] * inv, ga[5] * inv);
        q0.w = pkbf(ga[6] * inv, ga[7] * inv);
        q1.x = pkbf(ga[8] * inv, ga[9] * inv);
        q1.y = pkbf(ga[10] * inv, ga[11] * inv);
        q1.z = pkbf(ga[12] * inv, ga[13] * inv);
        q1.w = pkbf(ga[14] * inv, ga[15] * inv);
        nf[2 * hw]     = __builtin_bit_cast(short8, q0);
        nf[2 * hw + 1] = __builtin_bit_cast(short8, q1);
      }
    }

    __syncthreads();  // weights visible

    // bias -> accumulator init
    const float* be = bl + e * DD;
    f32x4 acc[8];
    #pragma unroll
    for (int c = 0; c < 8; ++c) {
      float bv = be[c * 16 + ln15];
      acc[c] = (f32x4){bv, bv, bv, bv};
    }

    // self half: h @ Ws_e  (weights via swizzled ds_read_b128)
    #pragma unroll
    for (int ks = 0; ks < 4; ++ks) {
      int so = ((ks * 4 + kg) ^ rx) << 3;
      #pragma unroll
      for (int c = 0; c < 8; ++c) {
        short8 bfr = *(const short8*)(&wbuf[(c * 16 + ln15) * DD + so]);
        acc[c] = __builtin_amdgcn_mfma_f32_16x16x32_bf16(hf[ks], bfr, acc[c], 0, 0, 0);
      }
    }
    // neigh half: ng_e @ Wn_e
    #pragma unroll
    for (int ks = 0; ks < 4; ++ks) {
      int so = ((ks * 4 + kg) ^ rx) << 3;
      #pragma unroll
      for (int c = 0; c < 8; ++c) {
        short8 bfr = *(const short8*)(&wbuf[(128 + c * 16 + ln15) * DD + so]);
        acc[c] = __builtin_amdgcn_mfma_f32_16x16x32_bf16(nf[ks], bfr, acc[c], 0, 0, 0);
      }
    }

    // per-etype activation, merge into out
    #pragma unroll
    for (int c = 0; c < 8; ++c) {
      #pragma unroll
      for (int r = 0; r < 4; ++r) {
        float v = acc[c][r];
        if (ACT) v = fmaxf(v, 0.f);
        out[c][r] = (e == 0) ? v : (out[c][r] + v);
      }
    }
  }

  __syncthreads();  // done with wbuf; reuse as fp32 [128][128] scratch
  float* scr = (float*)wbuf;

  // scatter fragments (C/D layout: col=lane&15, row=(lane>>4)*4+reg)
  int drow = wv * 16 + kg * 4;
  #pragma unroll
  for (int c = 0; c < 8; ++c) {
    int colx = c * 16 + ln15;
    #pragma unroll
    for (int r = 0; r < 4; ++r) scr[(drow + r) * DD + colx] = out[c][r];
  }
  __syncthreads();

  // coalesced write-out + per-thread column partial sums for BN
  int ty = tid >> 5;
  int c4 = (tid & 31) * 4;
  f32x4 s = (f32x4){0.f, 0.f, 0.f, 0.f};
  f32x4 s2 = (f32x4){0.f, 0.f, 0.f, 0.f};
  #pragma unroll
  for (int it = 0; it < 8; ++it) {
    int row = it * 16 + ty;
    int grow = row0 + row;
    if (grow < NN) {
      f32x4 v = *(const f32x4*)(scr + row * DD + c4);
      *(f32x4*)(P + (size_t)grow * DD + c4) = v;
      s += v;
      s2 += v * v;
    }
  }
  __syncthreads();
  *(f32x4*)(scr + ty * DD + c4) = s;
  *(f32x4*)(scr + 16 * DD + ty * DD + c4) = s2;
  __syncthreads();
  if (tid < DD) {
    float ts = 0.f, ts2 = 0.f;
    #pragma unroll
    for (int g = 0; g < 16; ++g) {
      ts += scr[g * DD + tid];
      ts2 += scr[16 * DD + g * DD + tid];
    }
    atomicAdd(gsums + tid, ts);
    atomicAdd(gsums + DD + tid, ts2);
  }
}

// ---------------- batchnorm finalize / apply ----------------

__global__ __launch_bounds__(128) void bn_finalize_kernel(const float* __restrict__ sums,
                                                          const float* __restrict__ gamma,
                                                          const float* __restrict__ beta,
                                                          float* __restrict__ ss) {
  int c = threadIdx.x;
  float mean = sums[c] * (1.0f / NN);
  float var = sums[DD + c] * (1.0f / NN) - mean * mean;
  float sc = gamma[c] * rsqrtf(var + EPSV);
  ss[c] = sc;
  ss[DD + c] = beta[c] - mean * sc;
}

template <bool LASTL>
__global__ __launch_bounds__(256) void bn_apply(const float* __restrict__ P,
                                                const float* __restrict__ ss,
                                                unsigned short* __restrict__ hb,
                                                float* __restrict__ outp) {
  const int n4 = NN * DD / 4;
  for (int i = blockIdx.x * 256 + threadIdx.x; i < n4; i += gridDim.x * 256) {
    int c4 = (i & 31) << 2;
    float4 v = ((const float4*)P)[i];
    float4 sc = *(const float4*)(ss + c4);
    float4 sh = *(const float4*)(ss + DD + c4);
    v.x = v.x * sc.x + sh.x;
    v.y = v.y * sc.y + sh.y;
    v.z = v.z * sc.z + sh.z;
    v.w = v.w * sc.w + sh.w;
    if (LASTL) {
      ((float4*)outp)[i] = v;
    } else {
      ushort4 o = make_ushort4(f2bf(v.x), f2bf(v.y), f2bf(v.z), f2bf(v.w));
      ((ushort4*)hb)[i] = o;
    }
  }
}

// ---------------- launch ----------------

static inline size_t align_up(size_t x, size_t a) { return (x + a - 1) & ~(a - 1); }

extern "C" void kernel_launch(void* const* d_in, const int* in_sizes, int n_in,
                              void* d_out, int out_size, void* d_ws, size_t ws_size,
                              hipStream_t stream) {
  const float* feat    = (const float*)d_in[0];
  const int*   src     = (const int*)d_in[1];
  const int*   dst     = (const int*)d_in[2];
  const float* W_self  = (const float*)d_in[3];
  const float* W_neigh = (const float*)d_in[4];
  const float* b       = (const float*)d_in[5];
  const float* gamma   = (const float*)d_in[6];
  const float* beta    = (const float*)d_in[7];

  float* P = (float*)d_out;  // fp32 pre-BN accumulator in d_out

  char* w = (char*)d_ws;
  size_t off = 0;
  unsigned short* hbf = (unsigned short*)(w + off); off = align_up(off + (size_t)NN * DD * 2, 256);
  unsigned short* wt  = (unsigned short*)(w + off); off = align_up(off + (size_t)2 * NL * NT * DD * DD * 2, 256);
  int* rp  = (int*)(w + off); off = align_up(off + (size_t)NT * (NN + 1) * 4, 256);
  int* col = (int*)(w + off); off = align_up(off + (size_t)NT * NE * 4, 256);
  float* gsums = (float*)(w + off); off = align_up(off + 256 * 4, 256);
  float* ss    = (float*)(w + off); off = align_up(off + 256 * 4, 256);
  int* cnt = (int*)(w + off); off = align_up(off + (size_t)NT * NN * 4, 256);
  int* aux = (int*)(w + off); off = align_up(off + (size_t)NT * SCB * 4, 256);

  // ---- CSR build ----
  hipMemsetAsync(cnt, 0, (size_t)NT * NN * 4, stream);
  count_kernel<<<(NT * NE + 255) / 256, 256, 0, stream>>>(dst, cnt);
  scanA<<<NT * SCB, 256, 0, stream>>>(cnt, rp, aux);
  scanB<<<1, 64, 0, stream>>>(aux, rp);
  scanC<<<NT * SCB, 256, 0, stream>>>(rp, aux);
  hipMemsetAsync(cnt, 0, (size_t)NT * NN * 4, stream);
  fill_kernel<<<(NT * NE + 255) / 256, 256, 0, stream>>>(src, dst, rp, cnt, col);

  // ---- conversions ----
  convert_wt<<<(2 * NL * NT * DD * DD + 255) / 256, 256, 0, stream>>>(W_self, W_neigh, wt);
  convert_f2b<<<1024, 256, 0, stream>>>(feat, hbf);

  const int gemm_grid = (NN + 127) / 128;
  for (int l = 0; l < NL; ++l) {
    bool act = (l < NL - 1);
    hipMemsetAsync(gsums, 0, 256 * 4, stream);
    const unsigned short* wtl = wt + (size_t)l * NT * 2 * DD * DD;
    const float* bl = b + (size_t)l * NT * DD;
    if (act) gemm_fused<true><<<gemm_grid, 512, 0, stream>>>(hbf, rp, col, wtl, bl, P, gsums);
    else     gemm_fused<false><<<gemm_grid, 512, 0, stream>>>(hbf, rp, col, wtl, bl, P, gsums);
    bn_finalize_kernel<<<1, 128, 0, stream>>>(gsums, gamma + l * DD, beta + l * DD, ss);
    if (l == NL - 1) bn_apply<true><<<1024, 256, 0, stream>>>(P, ss, hbf, P);
    else             bn_apply<false><<<1024, 256, 0, stream>>>(P, ss, hbf, P);
  }
}